// Round 3
// baseline (39.112 us; speedup 1.0000x reference)
//
#include <hip/hip_runtime.h>

#define NB 32
#define NS 8192
#define ND 64
#define CHUNK 256
#define NCHUNK (NS / CHUNK)   // 32
#define INV_T 0.125f          // 1/8.0
#define PSTRIDE 68            // m, l, pad, pad, acc[64]  (acc 16B-aligned)
#define NPART_PER_B (NCHUNK * 4)   // per-wave partials: 128 per batch

// ---------------- Phase 1: per-(batch, chunk) partial flash attention -----
// Group-of-16 fragment layout, all 32 loads (16 K + 16 V) issued up front,
// per-WAVE softmax max -> zero barriers, zero LDS in this kernel.
__global__ __launch_bounds__(256) void attn_p1(
    const float* __restrict__ q, const float* __restrict__ k,
    const float* __restrict__ v, float* __restrict__ attn,
    float* __restrict__ part)
{
    const int blk = blockIdx.x;       // 0 .. NB*NCHUNK-1
    const int b   = blk >> 5;         // / NCHUNK
    const int c   = blk & (NCHUNK - 1);
    const int tid = threadIdx.x;
    const int w   = tid >> 6;         // wave 0..3
    const int l   = tid & 63;         // lane
    const int l16 = l & 15;           // lane within 16-group (owns 4 dims)
    const int g   = l >> 4;           // group 0..3

    const size_t kb    = (size_t)b * NS * ND;
    const int    rbase = c * CHUNK + w * 64 + g * 16;  // group's first row

    const float4  qv = *reinterpret_cast<const float4*>(q + b * ND + l16 * 4);
    const float4* kp = reinterpret_cast<const float4*>(k + kb);
    const float4* vp = reinterpret_cast<const float4*>(v + kb);

    // ---- issue all 32 loads before any use (deep MLP)
    float4 kf[16], vf[16];
#pragma unroll
    for (int j = 0; j < 16; ++j)
        kf[j] = kp[(size_t)(rbase + j) * (ND / 4) + l16];
#pragma unroll
    for (int j = 0; j < 16; ++j)
        vf[j] = vp[(size_t)(rbase + j) * (ND / 4) + l16];
    asm volatile("" ::: "memory");   // pin load-issue point

    // ---- dots: group's 16 rows; after shuffles all 16 lanes hold each dot
    float s[16];
#pragma unroll
    for (int j = 0; j < 16; ++j) {
        float p = kf[j].x * qv.x + kf[j].y * qv.y +
                  kf[j].z * qv.z + kf[j].w * qv.w;
        p += __shfl_xor(p, 1);
        p += __shfl_xor(p, 2);
        p += __shfl_xor(p, 4);
        p += __shfl_xor(p, 8);
        s[j] = p * INV_T;
    }

    // ---- coalesced raw-score store; static select tree (no runtime index)
    float sc = s[0];
#pragma unroll
    for (int j = 1; j < 16; ++j) sc = (l16 == j) ? s[j] : sc;
    attn[(size_t)b * NS + c * CHUNK + w * 64 + l] = sc;

    // ---- per-WAVE max (p2 renormalizes globally; no block barrier needed)
    float m = s[0];
#pragma unroll
    for (int j = 1; j < 16; ++j) m = fmaxf(m, s[j]);
    m = fmaxf(m, __shfl_xor(m, 16));
    m = fmaxf(m, __shfl_xor(m, 32));

    // ---- exp + wave l
    float e[16];
    float ls = 0.f;
#pragma unroll
    for (int j = 0; j < 16; ++j) { e[j] = __expf(s[j] - m); ls += e[j]; }
    ls += __shfl_xor(ls, 16);
    ls += __shfl_xor(ls, 32);

    // ---- V accumulate (vf already in flight since the top)
    float4 acc = make_float4(0.f, 0.f, 0.f, 0.f);
#pragma unroll
    for (int j = 0; j < 16; ++j) {
        acc.x += e[j] * vf[j].x; acc.y += e[j] * vf[j].y;
        acc.z += e[j] * vf[j].z; acc.w += e[j] * vf[j].w;
    }
    acc.x += __shfl_xor(acc.x, 16); acc.y += __shfl_xor(acc.y, 16);
    acc.z += __shfl_xor(acc.z, 16); acc.w += __shfl_xor(acc.w, 16);
    acc.x += __shfl_xor(acc.x, 32); acc.y += __shfl_xor(acc.y, 32);
    acc.z += __shfl_xor(acc.z, 32); acc.w += __shfl_xor(acc.w, 32);

    // ---- per-wave partial out
    float* pp = part + (size_t)(blk * 4 + w) * PSTRIDE;
    if (l == 0) { pp[0] = m; pp[1] = ls; }
    if (l < 16) reinterpret_cast<float4*>(pp + 4)[l16] = acc;
}

// ---------------- Phase 2: reduce 128 wave-partials per batch -------------
__global__ __launch_bounds__(256) void attn_p2(
    const float* __restrict__ part, float* __restrict__ out,
    float* __restrict__ stats)
{
    const int b = blockIdx.x;
    const int w = threadIdx.x >> 6;
    const int l = threadIdx.x & 63;
    const float* pb = part + (size_t)b * NPART_PER_B * PSTRIDE;

    __shared__ float wm[4], wl[4], wacc[4][ND];

    float m = -1e30f;
#pragma unroll 8
    for (int i = 0; i < 32; ++i)
        m = fmaxf(m, pb[(w * 32 + i) * PSTRIDE]);
    if (l == 0) wm[w] = m;
    __syncthreads();
    const float M = fmaxf(fmaxf(wm[0], wm[1]), fmaxf(wm[2], wm[3]));

    float ls = 0.f, acc = 0.f;
#pragma unroll 8
    for (int i = 0; i < 32; ++i) {
        const float* pe = pb + (w * 32 + i) * PSTRIDE;
        const float wgt = __expf(pe[0] - M);
        ls  += pe[1] * wgt;
        acc += pe[4 + l] * wgt;
    }
    if (l == 0) wl[w] = ls;
    wacc[w][l] = acc;
    __syncthreads();

    if (w == 0) {
        const float lt = wl[0] + wl[1] + wl[2] + wl[3];
        const float a  = wacc[0][l] + wacc[1][l] + wacc[2][l] + wacc[3][l];
        const float invl = 1.f / lt;
        out[b * ND + l] = a * invl;
        if (l == 0) { stats[b * 2] = M; stats[b * 2 + 1] = invl; }
    }
}

// ---------------- Phase 3: rescale raw scores -> probabilities ------------
__global__ __launch_bounds__(256) void attn_p3(
    float* __restrict__ attn, const float* __restrict__ stats)
{
    const int idx = blockIdx.x * 256 + threadIdx.x;  // over NB*NS/4 float4s
    const int b = idx >> 11;                         // NS/4 = 2048 per batch
    const float m    = stats[b * 2];
    const float invl = stats[b * 2 + 1];
    float4 sv = reinterpret_cast<float4*>(attn)[idx];
    sv.x = __expf(sv.x - m) * invl;
    sv.y = __expf(sv.y - m) * invl;
    sv.z = __expf(sv.z - m) * invl;
    sv.w = __expf(sv.w - m) * invl;
    reinterpret_cast<float4*>(attn)[idx] = sv;
}

extern "C" void kernel_launch(void* const* d_in, const int* in_sizes, int n_in,
                              void* d_out, int out_size, void* d_ws, size_t ws_size,
                              hipStream_t stream)
{
    const float* q = (const float*)d_in[0];   // [32, 64]
    const float* k = (const float*)d_in[1];   // [32, 8192, 64]
    const float* v = (const float*)d_in[2];   // [32, 8192, 64]

    float* out  = (float*)d_out;              // [32,1,64]  -> 2048 floats
    float* attn = out + NB * ND;              // [32,1,8192]-> 262144 floats

    float* part  = (float*)d_ws;              // [NB*NCHUNK*4][68]
    float* stats = part + (size_t)NB * NCHUNK * 4 * PSTRIDE; // [NB][2]

    attn_p1<<<NB * NCHUNK, 256, 0, stream>>>(q, k, v, attn, part);
    attn_p2<<<NB, 256, 0, stream>>>(part, out, stats);
    attn_p3<<<(NB * NS / 4) / 256, 256, 0, stream>>>(attn, stats);
}